// Round 7
// baseline (1155.756 us; speedup 1.0000x reference)
//
#include <hip/hip_runtime.h>
#include <hip/hip_bf16.h>

typedef __attribute__((ext_vector_type(8))) short short8;
typedef __attribute__((ext_vector_type(4))) float floatx4;

#define S_LEN  50
#define BATCH  128
#define DIM    512
#define HID    512
#define G3     1536
#define VOCAB  30000
#define TOKENS 6400
#define NVB    ((VOCAB + 127) / 128)   // 235 v-chunks in decode

__device__ __forceinline__ float bf2f(short u) {
    union { unsigned int i; float f; } c;
    c.i = ((unsigned int)(unsigned short)u) << 16;
    return c.f;
}
__device__ __forceinline__ unsigned short f2bf(float x) {
    __hip_bfloat16 h = __float2bfloat16(x);
    unsigned short u;
    __builtin_memcpy(&u, &h, 2);
    return u;
}

// ---------------- f32 -> bf16 bulk convert (8 elems/thread) ----------------
__global__ void k_cvt_bf16(const float* __restrict__ src,
                           unsigned short* __restrict__ dst, int n8) {
    int g = blockIdx.x * 256 + threadIdx.x;
    if (g >= n8) return;
    const float* s = src + (size_t)g * 8;
    union { short8 v; unsigned short u[8]; } o;
#pragma unroll
    for (int i = 0; i < 8; ++i) o.u[i] = f2bf(s[i]);
    *(short8*)(dst + (size_t)g * 8) = o.v;
}

// ---------------- embedding gather + convert: X[token][512] bf16 ----------------
__global__ void k_gather_x(const float* __restrict__ emb, const int* __restrict__ idx,
                           unsigned short* __restrict__ X) {
    int g = blockIdx.x * 256 + threadIdx.x;   // 8-elem group; total TOKENS*DIM/8
    int token = g >> 6;                       // 64 groups per token
    int chunk = (g & 63) << 3;
    const float* src = emb + (size_t)idx[token] * DIM + chunk;
    union { short8 v; unsigned short u[8]; } o;
#pragma unroll
    for (int i = 0; i < 8; ++i) o.u[i] = f2bf(src[i]);
    *(short8*)(X + (size_t)token * DIM + chunk) = o.v;
}

// ---------------- GI = X @ W_ih^T + b_ih   [6400 x 1536] fp32 ----------------
// NT GEMM, bf16 MFMA 16x16x32. Block: 256 thr (4 waves), tile 64x64, BK=64.
__launch_bounds__(256)
__global__ void k_gemm_gi(const unsigned short* __restrict__ X,
                          const unsigned short* __restrict__ Wih,
                          const float* __restrict__ b_ih,
                          float* __restrict__ GI) {
    __shared__ unsigned short As[64][72];
    __shared__ unsigned short Bs[64][72];
    int m0 = blockIdx.x * 64;
    int n0 = blockIdx.y * 64;
    int t = threadIdx.x;
    int w = t >> 6, lane = t & 63;
    floatx4 zero = {0.f, 0.f, 0.f, 0.f};
    floatx4 acc[4];
#pragma unroll
    for (int i = 0; i < 4; ++i) acc[i] = zero;
    int srow = t >> 2, scol = (t & 3) * 16;
    for (int k0 = 0; k0 < DIM; k0 += 64) {
        *(short8*)&As[srow][scol]     = *(const short8*)(X   + (size_t)(m0 + srow) * DIM + k0 + scol);
        *(short8*)&As[srow][scol + 8] = *(const short8*)(X   + (size_t)(m0 + srow) * DIM + k0 + scol + 8);
        *(short8*)&Bs[srow][scol]     = *(const short8*)(Wih + (size_t)(n0 + srow) * DIM + k0 + scol);
        *(short8*)&Bs[srow][scol + 8] = *(const short8*)(Wih + (size_t)(n0 + srow) * DIM + k0 + scol + 8);
        __syncthreads();
#pragma unroll
        for (int kt = 0; kt < 2; ++kt) {
            short8 a = *(const short8*)&As[w * 16 + (lane & 15)][kt * 32 + (lane >> 4) * 8];
#pragma unroll
            for (int nt = 0; nt < 4; ++nt) {
                short8 b = *(const short8*)&Bs[nt * 16 + (lane & 15)][kt * 32 + (lane >> 4) * 8];
                acc[nt] = __builtin_amdgcn_mfma_f32_16x16x32_bf16(a, b, acc[nt], 0, 0, 0);
            }
        }
        __syncthreads();
    }
#pragma unroll
    for (int nt = 0; nt < 4; ++nt)
#pragma unroll
        for (int r = 0; r < 4; ++r) {
            int row = m0 + w * 16 + (lane >> 4) * 4 + r;
            int col = n0 + nt * 16 + (lane & 15);
            GI[(size_t)row * G3 + col] = acc[nt][r] + b_ih[col];
        }
}

// ---------------- persistent GRU: 128 blocks, 50 steps, atomic barrier ----------------
// Block = (batch group bg of 16 rows) x (hidden slice hs of 32 units); identical
// per-step math to the round-5 k_gru_step. Cross-block h exchange protected by a
// monotonic agent-scope counter barrier (release add / acquire spin + threadfence).
__launch_bounds__(128)
__global__ void k_gru_persist(const float* __restrict__ GI,
                              const unsigned short* __restrict__ Whh,
                              const float* __restrict__ b_hh,
                              float* __restrict__ hf,
                              const unsigned short* __restrict__ hzero,
                              unsigned short* __restrict__ HS,
                              unsigned int* __restrict__ counter) {
    int t = threadIdx.x;
    int w = t >> 6, lane = t & 63;
    int bg = blockIdx.x & 7;      // batch group
    int hs = blockIdx.x >> 3;     // hidden slice (16 slices of 32)
    int jc = hs * 32 + w * 16 + (lane & 15);   // hidden unit (N index)

    const unsigned short* pb0 = Whh + (size_t)(0 * HID + jc) * DIM + (lane >> 4) * 8;
    const unsigned short* pb1 = Whh + (size_t)(1 * HID + jc) * DIM + (lane >> 4) * 8;
    const unsigned short* pb2 = Whh + (size_t)(2 * HID + jc) * DIM + (lane >> 4) * 8;
    float bhr = b_hh[jc], bhz = b_hh[jc + 512], bhn = b_hh[jc + 1024];

    for (int s = 0; s < S_LEN; ++s) {
        const unsigned short* hin = s ? (HS + (size_t)(s - 1) * BATCH * HID) : hzero;
        unsigned short* hout = HS + (size_t)s * BATCH * HID;
        const unsigned short* pa = hin + (size_t)(bg * 16 + (lane & 15)) * HID + (lane >> 4) * 8;

        floatx4 acc0 = {0.f, 0.f, 0.f, 0.f};
        floatx4 acc1 = {0.f, 0.f, 0.f, 0.f};
        floatx4 acc2 = {0.f, 0.f, 0.f, 0.f};
#pragma unroll
        for (int kt = 0; kt < 16; ++kt) {
            short8 a = *(const short8*)(pa + kt * 32);
            acc0 = __builtin_amdgcn_mfma_f32_16x16x32_bf16(a, *(const short8*)(pb0 + kt * 32), acc0, 0, 0, 0);
            acc1 = __builtin_amdgcn_mfma_f32_16x16x32_bf16(a, *(const short8*)(pb1 + kt * 32), acc1, 0, 0, 0);
            acc2 = __builtin_amdgcn_mfma_f32_16x16x32_bf16(a, *(const short8*)(pb2 + kt * 32), acc2, 0, 0, 0);
        }
#pragma unroll
        for (int r = 0; r < 4; ++r) {
            int brow = bg * 16 + (lane >> 4) * 4 + r;   // batch row (M index)
            int tok = s * BATCH + brow;
            const float* gi = GI + (size_t)tok * G3;
            float rg = 1.f / (1.f + __expf(-(gi[jc] + acc0[r] + bhr)));
            float zg = 1.f / (1.f + __expf(-(gi[jc + 512] + acc1[r] + bhz)));
            float ng = tanhf(gi[jc + 1024] + rg * (acc2[r] + bhn));
            size_t hidx = (size_t)brow * HID + jc;
            float hn = (1.f - zg) * ng + zg * hf[hidx];
            hf[hidx] = hn;
            hout[hidx] = f2bf(hn);
        }

        // ---- grid barrier: all 128 blocks finish step s before any reads it ----
        __syncthreads();                       // block's stores issued & drained
        if (t == 0) {
            __threadfence();                   // device-scope release of our writes
            __hip_atomic_fetch_add(counter, 1u, __ATOMIC_RELEASE, __HIP_MEMORY_SCOPE_AGENT);
            unsigned int target = 128u * (unsigned int)(s + 1);
            while (__hip_atomic_load(counter, __ATOMIC_ACQUIRE, __HIP_MEMORY_SCOPE_AGENT) < target)
                __builtin_amdgcn_s_sleep(2);
            __threadfence();                   // acquire: invalidate stale cache lines
        }
        __syncthreads();
    }
}

// ---------------- decode: partial sum(exp(logit)) per (token, v-chunk) ----------------
// Block: 256 thr (4 waves), tile M=64 tokens x N=128 vocab, BK=64. (round-5 proven)
__launch_bounds__(256)
__global__ void k_decode(const unsigned short* __restrict__ HS,
                         const unsigned short* __restrict__ Wout,
                         const float* __restrict__ b_out,
                         float* __restrict__ partial) {
    __shared__ unsigned short As[64][72];
    __shared__ unsigned short Bs[128][72];
    int m0 = blockIdx.x * 64;
    int nb = blockIdx.y;
    int n0 = nb * 128;
    int t = threadIdx.x, w = t >> 6, lane = t & 63;
    floatx4 zero = {0.f, 0.f, 0.f, 0.f};
    floatx4 acc[8];
#pragma unroll
    for (int i = 0; i < 8; ++i) acc[i] = zero;
    int arow = t >> 2, acol = (t & 3) * 16;
    int brow = t >> 1, bcol = (t & 1) * 32;
    short8 z8 = {0, 0, 0, 0, 0, 0, 0, 0};
    for (int k0 = 0; k0 < DIM; k0 += 64) {
        *(short8*)&As[arow][acol]     = *(const short8*)(HS + (size_t)(m0 + arow) * DIM + k0 + acol);
        *(short8*)&As[arow][acol + 8] = *(const short8*)(HS + (size_t)(m0 + arow) * DIM + k0 + acol + 8);
        int v = n0 + brow;
        if (v < VOCAB) {
            const unsigned short* wp = Wout + (size_t)v * DIM + k0 + bcol;
#pragma unroll
            for (int q = 0; q < 4; ++q)
                *(short8*)&Bs[brow][bcol + q * 8] = *(const short8*)(wp + q * 8);
        } else {
#pragma unroll
            for (int q = 0; q < 4; ++q) *(short8*)&Bs[brow][bcol + q * 8] = z8;
        }
        __syncthreads();
#pragma unroll
        for (int kt = 0; kt < 2; ++kt) {
            short8 a = *(const short8*)&As[w * 16 + (lane & 15)][kt * 32 + (lane >> 4) * 8];
#pragma unroll
            for (int nt = 0; nt < 8; ++nt) {
                short8 b = *(const short8*)&Bs[nt * 16 + (lane & 15)][kt * 32 + (lane >> 4) * 8];
                acc[nt] = __builtin_amdgcn_mfma_f32_16x16x32_bf16(a, b, acc[nt], 0, 0, 0);
            }
        }
        __syncthreads();
    }
    float esum[4] = {0.f, 0.f, 0.f, 0.f};
#pragma unroll
    for (int nt = 0; nt < 8; ++nt) {
        int v = n0 + nt * 16 + (lane & 15);
        bool ok = v < VOCAB;
        float bo = ok ? b_out[v] : 0.f;
#pragma unroll
        for (int r = 0; r < 4; ++r) {
            float logit = acc[nt][r] + bo;
            esum[r] += ok ? __expf(logit) : 0.f;
        }
    }
#pragma unroll
    for (int d = 1; d < 16; d <<= 1)
#pragma unroll
        for (int r = 0; r < 4; ++r) esum[r] += __shfl_xor(esum[r], d, 64);
    if ((lane & 15) == 0) {
#pragma unroll
        for (int r = 0; r < 4; ++r) {
            int tok = m0 + w * 16 + (lane >> 4) * 4 + r;
            partial[(size_t)tok * 256 + nb] = esum[r];
        }
    }
}

// ---------------- fixed-order reduce of partials -> lse ----------------
__global__ void k_reduce_lse(const float* __restrict__ partial, float* __restrict__ lse) {
    int tok = blockIdx.x * 4 + (threadIdx.x >> 6);
    int lane = threadIdx.x & 63;
    float s = 0.f;
    for (int j = lane; j < NVB; j += 64) s += partial[(size_t)tok * 256 + j];
#pragma unroll
    for (int d = 1; d < 64; d <<= 1) s += __shfl_xor(s, d, 64);
    if (lane == 0) lse[tok] = logf(s);
}

// ---------------- target logit: one wave per token ----------------
__global__ void k_tlogit(const unsigned short* __restrict__ HS,
                         const unsigned short* __restrict__ Wout,
                         const float* __restrict__ b_out,
                         const int* __restrict__ target,
                         float* __restrict__ tlg) {
    int tok = blockIdx.x * 4 + (threadIdx.x >> 6);
    int lane = threadIdx.x & 63;
    int tg = target[tok];
    short8 a = *(const short8*)(HS + (size_t)tok * DIM + lane * 8);
    short8 b = *(const short8*)(Wout + (size_t)tg * DIM + lane * 8);
    float s = 0.f;
#pragma unroll
    for (int i = 0; i < 8; ++i) s += bf2f(a[i]) * bf2f(b[i]);
#pragma unroll
    for (int d = 1; d < 64; d <<= 1) s += __shfl_xor(s, d, 64);
    if (lane == 0) tlg[tok] = s + b_out[tg];
}

// ---------------- loss + masked mean ----------------
__global__ void k_finalize(const float* __restrict__ lse, const float* __restrict__ tlg,
                           const int* __restrict__ target, float* __restrict__ out) {
    __shared__ float ssum[256];
    __shared__ float scnt[256];
    int t = threadIdx.x;
    float ls = 0.f, lc = 0.f;
    for (int i = t; i < TOKENS; i += 256) {
        int tg = target[i];
        float loss = (tg != 0) ? (lse[i] - tlg[i]) : 0.f;
        out[i] = loss;
        ls += loss;
        lc += (tg != 0) ? 1.f : 0.f;
    }
    ssum[t] = ls; scnt[t] = lc;
    __syncthreads();
    for (int d = 128; d > 0; d >>= 1) {
        if (t < d) { ssum[t] += ssum[t + d]; scnt[t] += scnt[t + d]; }
        __syncthreads();
    }
    if (t == 0) out[TOKENS] = ssum[0] / fmaxf(scnt[0], 1.f);
}

extern "C" void kernel_launch(void* const* d_in, const int* in_sizes, int n_in,
                              void* d_out, int out_size, void* d_ws, size_t ws_size,
                              hipStream_t stream) {
    const int*   review_input  = (const int*)d_in[2];
    const int*   review_target = (const int*)d_in[3];
    const float* word_emb      = (const float*)d_in[4];
    const float* W_ih          = (const float*)d_in[5];
    const float* W_hh          = (const float*)d_in[6];
    const float* b_ih          = (const float*)d_in[7];
    const float* b_hh          = (const float*)d_in[8];
    const float* W_out         = (const float*)d_in[9];
    const float* b_out         = (const float*)d_in[10];
    float* out = (float*)d_out;

    char* ws = (char*)d_ws;
    size_t off = 0;
    auto alloc = [&](size_t n) { char* p = ws + off; off += (n + 255) & ~(size_t)255; return p; };
    unsigned short* Xb    = (unsigned short*)alloc((size_t)TOKENS * DIM * 2);
    unsigned short* Wihb  = (unsigned short*)alloc((size_t)G3 * DIM * 2);
    unsigned short* Whhb  = (unsigned short*)alloc((size_t)G3 * HID * 2);
    unsigned short* Woutb = (unsigned short*)alloc((size_t)VOCAB * DIM * 2);
    unsigned short* HS    = (unsigned short*)alloc((size_t)TOKENS * HID * 2);
    unsigned short* hzero = (unsigned short*)alloc((size_t)BATCH * HID * 2);
    float* hf      = (float*)alloc((size_t)BATCH * HID * 4);
    float* GI      = (float*)alloc((size_t)TOKENS * G3 * 4);
    float* partial = (float*)alloc((size_t)TOKENS * 256 * 4);
    float* lse     = (float*)alloc((size_t)TOKENS * 4);
    float* tlg     = (float*)alloc((size_t)TOKENS * 4);
    unsigned int* counter = (unsigned int*)alloc(256);
    (void)ws_size; (void)in_sizes; (void)n_in; (void)out_size;

    // weight conversions + embedding gather
    k_cvt_bf16<<<dim3((G3 * DIM / 8 + 255) / 256), dim3(256), 0, stream>>>(W_ih, Wihb, G3 * DIM / 8);
    k_cvt_bf16<<<dim3((G3 * HID / 8 + 255) / 256), dim3(256), 0, stream>>>(W_hh, Whhb, G3 * HID / 8);
    k_cvt_bf16<<<dim3((VOCAB * DIM / 8 + 255) / 256), dim3(256), 0, stream>>>(W_out, Woutb, VOCAB * DIM / 8);
    k_gather_x<<<dim3(TOKENS * DIM / 8 / 256), dim3(256), 0, stream>>>(word_emb, review_input, Xb);

    // GI = X @ W_ih^T + b_ih
    k_gemm_gi<<<dim3(TOKENS / 64, G3 / 64), dim3(256), 0, stream>>>(Xb, Wihb, b_ih, GI);

    // GRU recurrence: one persistent kernel, internal atomic barrier per step
    hipMemsetAsync(hf, 0, (size_t)BATCH * HID * 4, stream);
    hipMemsetAsync(hzero, 0, (size_t)BATCH * HID * 2, stream);
    hipMemsetAsync(counter, 0, 256, stream);
    k_gru_persist<<<dim3(128), dim3(128), 0, stream>>>(GI, Whhb, b_hh, hf, hzero, HS, counter);

    // decode: partial exp-sums, reduce to lse, target logits, final loss
    k_decode<<<dim3(TOKENS / 64, NVB), dim3(256), 0, stream>>>(HS, Woutb, b_out, partial);
    k_reduce_lse<<<dim3(TOKENS / 4), dim3(256), 0, stream>>>(partial, lse);
    k_tlogit<<<dim3(TOKENS / 4), dim3(256), 0, stream>>>(HS, Woutb, b_out, review_target, tlg);
    k_finalize<<<dim3(1), dim3(256), 0, stream>>>(lse, tlg, review_target, out);
}

// Round 9
// 630.265 us; speedup vs baseline: 1.8338x; 1.8338x over previous
//
#include <hip/hip_runtime.h>
#include <hip/hip_bf16.h>

typedef __attribute__((ext_vector_type(8))) short short8;
typedef __attribute__((ext_vector_type(4))) float floatx4;

#define S_LEN  50
#define BATCH  128
#define DIM    512
#define HID    512
#define G3     1536
#define VOCAB  30000
#define TOKENS 6400
#define NB256  118      // ceil(30000/256) vocab chunks in decode
#define NVC    472      // partial columns = NB256 * 4 waves
#define NWG    (25 * NB256)   // 2950 decode blocks

__device__ __forceinline__ float bf2f(short u) {
    union { unsigned int i; float f; } c;
    c.i = ((unsigned int)(unsigned short)u) << 16;
    return c.f;
}
__device__ __forceinline__ unsigned short f2bf(float x) {
    __hip_bfloat16 h = __float2bfloat16(x);
    unsigned short u;
    __builtin_memcpy(&u, &h, 2);
    return u;
}

// ---------------- f32 -> bf16 bulk convert (8 elems/thread) ----------------
__global__ void k_cvt_bf16(const float* __restrict__ src,
                           unsigned short* __restrict__ dst, int n8) {
    int g = blockIdx.x * 256 + threadIdx.x;
    if (g >= n8) return;
    const float* s = src + (size_t)g * 8;
    union { short8 v; unsigned short u[8]; } o;
#pragma unroll
    for (int i = 0; i < 8; ++i) o.u[i] = f2bf(s[i]);
    *(short8*)(dst + (size_t)g * 8) = o.v;
}

// ---------------- embedding gather + convert: X[token][512] bf16 ----------------
__global__ void k_gather_x(const float* __restrict__ emb, const int* __restrict__ idx,
                           unsigned short* __restrict__ X) {
    int g = blockIdx.x * 256 + threadIdx.x;   // 8-elem group; total TOKENS*DIM/8
    int token = g >> 6;                       // 64 groups per token
    int chunk = (g & 63) << 3;
    const float* src = emb + (size_t)idx[token] * DIM + chunk;
    union { short8 v; unsigned short u[8]; } o;
#pragma unroll
    for (int i = 0; i < 8; ++i) o.u[i] = f2bf(src[i]);
    *(short8*)(X + (size_t)token * DIM + chunk) = o.v;
}

// ---------------- GI = X @ W_ih^T + b_ih   [6400 x 1536] fp32 ----------------
__launch_bounds__(256)
__global__ void k_gemm_gi(const unsigned short* __restrict__ X,
                          const unsigned short* __restrict__ Wih,
                          const float* __restrict__ b_ih,
                          float* __restrict__ GI) {
    __shared__ unsigned short As[64][72];
    __shared__ unsigned short Bs[64][72];
    int m0 = blockIdx.x * 64;
    int n0 = blockIdx.y * 64;
    int t = threadIdx.x;
    int w = t >> 6, lane = t & 63;
    floatx4 zero = {0.f, 0.f, 0.f, 0.f};
    floatx4 acc[4];
#pragma unroll
    for (int i = 0; i < 4; ++i) acc[i] = zero;
    int srow = t >> 2, scol = (t & 3) * 16;
    for (int k0 = 0; k0 < DIM; k0 += 64) {
        *(short8*)&As[srow][scol]     = *(const short8*)(X   + (size_t)(m0 + srow) * DIM + k0 + scol);
        *(short8*)&As[srow][scol + 8] = *(const short8*)(X   + (size_t)(m0 + srow) * DIM + k0 + scol + 8);
        *(short8*)&Bs[srow][scol]     = *(const short8*)(Wih + (size_t)(n0 + srow) * DIM + k0 + scol);
        *(short8*)&Bs[srow][scol + 8] = *(const short8*)(Wih + (size_t)(n0 + srow) * DIM + k0 + scol + 8);
        __syncthreads();
#pragma unroll
        for (int kt = 0; kt < 2; ++kt) {
            short8 a = *(const short8*)&As[w * 16 + (lane & 15)][kt * 32 + (lane >> 4) * 8];
#pragma unroll
            for (int nt = 0; nt < 4; ++nt) {
                short8 b = *(const short8*)&Bs[nt * 16 + (lane & 15)][kt * 32 + (lane >> 4) * 8];
                acc[nt] = __builtin_amdgcn_mfma_f32_16x16x32_bf16(a, b, acc[nt], 0, 0, 0);
            }
        }
        __syncthreads();
    }
#pragma unroll
    for (int nt = 0; nt < 4; ++nt)
#pragma unroll
        for (int r = 0; r < 4; ++r) {
            int row = m0 + w * 16 + (lane >> 4) * 4 + r;
            int col = n0 + nt * 16 + (lane & 15);
            GI[(size_t)row * G3 + col] = acc[nt][r] + b_ih[col];
        }
}

// ---------------- GRU single step (round-5 proven): 128 blocks x 128 thr ----------------
__launch_bounds__(128)
__global__ void k_gru_step(const float* __restrict__ GI,
                           const unsigned short* __restrict__ Whh,
                           const float* __restrict__ b_hh,
                           float* __restrict__ hf,
                           const unsigned short* __restrict__ hin,
                           unsigned short* __restrict__ hout,
                           int s) {
    int t = threadIdx.x;
    int w = t >> 6, lane = t & 63;
    int bg = blockIdx.x & 7;      // batch group
    int hs = blockIdx.x >> 3;     // hidden slice (16 slices of 32)
    int jc = hs * 32 + w * 16 + (lane & 15);   // hidden unit (N index)

    const unsigned short* pa  = hin + (size_t)(bg * 16 + (lane & 15)) * HID + (lane >> 4) * 8;
    const unsigned short* pb0 = Whh + (size_t)(0 * HID + jc) * DIM + (lane >> 4) * 8;
    const unsigned short* pb1 = Whh + (size_t)(1 * HID + jc) * DIM + (lane >> 4) * 8;
    const unsigned short* pb2 = Whh + (size_t)(2 * HID + jc) * DIM + (lane >> 4) * 8;

    floatx4 acc0 = {0.f, 0.f, 0.f, 0.f};
    floatx4 acc1 = {0.f, 0.f, 0.f, 0.f};
    floatx4 acc2 = {0.f, 0.f, 0.f, 0.f};
#pragma unroll
    for (int kt = 0; kt < 16; ++kt) {
        short8 a = *(const short8*)(pa + kt * 32);
        acc0 = __builtin_amdgcn_mfma_f32_16x16x32_bf16(a, *(const short8*)(pb0 + kt * 32), acc0, 0, 0, 0);
        acc1 = __builtin_amdgcn_mfma_f32_16x16x32_bf16(a, *(const short8*)(pb1 + kt * 32), acc1, 0, 0, 0);
        acc2 = __builtin_amdgcn_mfma_f32_16x16x32_bf16(a, *(const short8*)(pb2 + kt * 32), acc2, 0, 0, 0);
    }
    float bhr = b_hh[jc], bhz = b_hh[jc + 512], bhn = b_hh[jc + 1024];
#pragma unroll
    for (int r = 0; r < 4; ++r) {
        int brow = bg * 16 + (lane >> 4) * 4 + r;   // batch row (M index)
        int tok = s * BATCH + brow;
        const float* gi = GI + (size_t)tok * G3;
        float rg = 1.f / (1.f + __expf(-(gi[jc] + acc0[r] + bhr)));
        float zg = 1.f / (1.f + __expf(-(gi[jc + 512] + acc1[r] + bhz)));
        float ng = tanhf(gi[jc + 1024] + rg * (acc2[r] + bhn));
        size_t hidx = (size_t)brow * HID + jc;
        float hn = (1.f - zg) * ng + zg * hf[hidx];
        hf[hidx] = hn;
        hout[hidx] = f2bf(hn);
    }
}

// ---------------- decode: 256x256 tile, 16 waves (4x4), XOR-swizzled LDS ----------------
// Per wave: 64x64 quadrant = 4x4 MFMA frags. BK=64, 8 K-iters. LDS 64 KB exact.
// Swizzle: byte ^= (row&7)<<4 on both ds_write and ds_read (bijective per 128B row).
__launch_bounds__(1024, 4)
__global__ void k_decode(const unsigned short* __restrict__ HS,
                         const unsigned short* __restrict__ Wout,
                         const float* __restrict__ b_out,
                         float* __restrict__ partial) {
    __shared__ unsigned short As[256 * 64];
    __shared__ unsigned short Bs[256 * 64];

    // bijective XCD chunk swizzle (nwg=2950, q=368, r=6)
    int bid = blockIdx.x;
    int xcd = bid & 7, pos = bid >> 3;
    int wgid = (xcd < 6 ? xcd * 369 : 2214 + (xcd - 6) * 368) + pos;
    int mb = wgid % 25, nb = wgid / 25;
    int m0 = mb * 256, n0 = nb * 256;

    int t = threadIdx.x, w = t >> 6, lane = t & 63;
    int wr = w >> 2, wc = w & 3;            // 4x4 wave grid

    floatx4 zero = {0.f, 0.f, 0.f, 0.f};
    floatx4 acc[4][4];
#pragma unroll
    for (int mi = 0; mi < 4; ++mi)
#pragma unroll
        for (int ni = 0; ni < 4; ++ni) acc[mi][ni] = zero;

    // staging: thread t owns row t>>2 (0..255), 32B chunk (t&3)
    int srow = t >> 2;
    int scb  = (t & 3) * 32;                // byte offset of 32B chunk within row
    int swz  = (srow & 7) << 4;
    const unsigned short* gA = HS + (size_t)(m0 + srow) * DIM + (t & 3) * 16;
    int vrow = n0 + srow; if (vrow > VOCAB - 1) vrow = VOCAB - 1;
    const unsigned short* gB = Wout + (size_t)vrow * DIM + (t & 3) * 16;
    char* wA0 = (char*)As + ((srow * 128 + scb)      ^ swz);
    char* wA1 = (char*)As + ((srow * 128 + scb + 16) ^ swz);
    char* wB0 = (char*)Bs + ((srow * 128 + scb)      ^ swz);
    char* wB1 = (char*)Bs + ((srow * 128 + scb + 16) ^ swz);

    for (int k0 = 0; k0 < DIM; k0 += 64) {
        short8 a0 = *(const short8*)(gA + k0);
        short8 a1 = *(const short8*)(gA + k0 + 8);
        short8 b0 = *(const short8*)(gB + k0);
        short8 b1 = *(const short8*)(gB + k0 + 8);
        *(short8*)wA0 = a0;
        *(short8*)wA1 = a1;
        *(short8*)wB0 = b0;
        *(short8*)wB1 = b1;
        __syncthreads();
#pragma unroll
        for (int kt = 0; kt < 2; ++kt) {
            short8 af[4], bf[4];
#pragma unroll
            for (int mi = 0; mi < 4; ++mi) {
                int row = wr * 64 + mi * 16 + (lane & 15);
                int off = (row * 128 + kt * 64 + (lane >> 4) * 16) ^ ((row & 7) << 4);
                af[mi] = *(const short8*)((const char*)As + off);
            }
#pragma unroll
            for (int ni = 0; ni < 4; ++ni) {
                int row = wc * 64 + ni * 16 + (lane & 15);
                int off = (row * 128 + kt * 64 + (lane >> 4) * 16) ^ ((row & 7) << 4);
                bf[ni] = *(const short8*)((const char*)Bs + off);
            }
#pragma unroll
            for (int mi = 0; mi < 4; ++mi)
#pragma unroll
                for (int ni = 0; ni < 4; ++ni)
                    acc[mi][ni] = __builtin_amdgcn_mfma_f32_16x16x32_bf16(af[mi], bf[ni], acc[mi][ni], 0, 0, 0);
        }
        __syncthreads();
    }

    // epilogue: exp + per-token partial sums over this wave's 64 vocab cols
    float esum[4][4];   // [mi][r]
#pragma unroll
    for (int mi = 0; mi < 4; ++mi)
#pragma unroll
        for (int r = 0; r < 4; ++r) esum[mi][r] = 0.f;
#pragma unroll
    for (int ni = 0; ni < 4; ++ni) {
        int v = n0 + wc * 64 + ni * 16 + (lane & 15);
        bool ok = v < VOCAB;
        float bo = ok ? b_out[v] : 0.f;
#pragma unroll
        for (int mi = 0; mi < 4; ++mi)
#pragma unroll
            for (int r = 0; r < 4; ++r) {
                float logit = acc[mi][ni][r] + bo;
                esum[mi][r] += ok ? __expf(logit) : 0.f;
            }
    }
#pragma unroll
    for (int d = 1; d < 16; d <<= 1)
#pragma unroll
        for (int mi = 0; mi < 4; ++mi)
#pragma unroll
            for (int r = 0; r < 4; ++r) esum[mi][r] += __shfl_xor(esum[mi][r], d, 64);
    if ((lane & 15) == 0) {
#pragma unroll
        for (int mi = 0; mi < 4; ++mi)
#pragma unroll
            for (int r = 0; r < 4; ++r) {
                int tok = m0 + wr * 64 + mi * 16 + (lane >> 4) * 4 + r;
                partial[(size_t)tok * 512 + nb * 4 + wc] = esum[mi][r];
            }
    }
}

// ---------------- fixed-order reduce of partials -> lse ----------------
__global__ void k_reduce_lse(const float* __restrict__ partial, float* __restrict__ lse) {
    int tok = blockIdx.x * 4 + (threadIdx.x >> 6);
    int lane = threadIdx.x & 63;
    float s = 0.f;
    for (int j = lane; j < NVC; j += 64) s += partial[(size_t)tok * 512 + j];
#pragma unroll
    for (int d = 1; d < 64; d <<= 1) s += __shfl_xor(s, d, 64);
    if (lane == 0) lse[tok] = logf(s);
}

// ---------------- target logit: one wave per token ----------------
__global__ void k_tlogit(const unsigned short* __restrict__ HS,
                         const unsigned short* __restrict__ Wout,
                         const float* __restrict__ b_out,
                         const int* __restrict__ target,
                         float* __restrict__ tlg) {
    int tok = blockIdx.x * 4 + (threadIdx.x >> 6);
    int lane = threadIdx.x & 63;
    int tg = target[tok];
    short8 a = *(const short8*)(HS + (size_t)tok * DIM + lane * 8);
    short8 b = *(const short8*)(Wout + (size_t)tg * DIM + lane * 8);
    float s = 0.f;
#pragma unroll
    for (int i = 0; i < 8; ++i) s += bf2f(a[i]) * bf2f(b[i]);
#pragma unroll
    for (int d = 1; d < 64; d <<= 1) s += __shfl_xor(s, d, 64);
    if (lane == 0) tlg[tok] = s + b_out[tg];
}

// ---------------- loss + masked mean ----------------
__global__ void k_finalize(const float* __restrict__ lse, const float* __restrict__ tlg,
                           const int* __restrict__ target, float* __restrict__ out) {
    __shared__ float ssum[256];
    __shared__ float scnt[256];
    int t = threadIdx.x;
    float ls = 0.f, lc = 0.f;
    for (int i = t; i < TOKENS; i += 256) {
        int tg = target[i];
        float loss = (tg != 0) ? (lse[i] - tlg[i]) : 0.f;
        out[i] = loss;
        ls += loss;
        lc += (tg != 0) ? 1.f : 0.f;
    }
    ssum[t] = ls; scnt[t] = lc;
    __syncthreads();
    for (int d = 128; d > 0; d >>= 1) {
        if (t < d) { ssum[t] += ssum[t + d]; scnt[t] += scnt[t + d]; }
        __syncthreads();
    }
    if (t == 0) out[TOKENS] = ssum[0] / fmaxf(scnt[0], 1.f);
}

extern "C" void kernel_launch(void* const* d_in, const int* in_sizes, int n_in,
                              void* d_out, int out_size, void* d_ws, size_t ws_size,
                              hipStream_t stream) {
    const int*   review_input  = (const int*)d_in[2];
    const int*   review_target = (const int*)d_in[3];
    const float* word_emb      = (const float*)d_in[4];
    const float* W_ih          = (const float*)d_in[5];
    const float* W_hh          = (const float*)d_in[6];
    const float* b_ih          = (const float*)d_in[7];
    const float* b_hh          = (const float*)d_in[8];
    const float* W_out         = (const float*)d_in[9];
    const float* b_out         = (const float*)d_in[10];
    float* out = (float*)d_out;

    char* ws = (char*)d_ws;
    size_t off = 0;
    auto alloc = [&](size_t n) { char* p = ws + off; off += (n + 255) & ~(size_t)255; return p; };
    unsigned short* Xb    = (unsigned short*)alloc((size_t)TOKENS * DIM * 2);
    unsigned short* Wihb  = (unsigned short*)alloc((size_t)G3 * DIM * 2);
    unsigned short* Whhb  = (unsigned short*)alloc((size_t)G3 * HID * 2);
    unsigned short* Woutb = (unsigned short*)alloc((size_t)VOCAB * DIM * 2);
    unsigned short* HS    = (unsigned short*)alloc((size_t)TOKENS * HID * 2);
    unsigned short* hzero = (unsigned short*)alloc((size_t)BATCH * HID * 2);
    float* hf      = (float*)alloc((size_t)BATCH * HID * 4);
    float* GI      = (float*)alloc((size_t)TOKENS * G3 * 4);
    float* partial = (float*)alloc((size_t)TOKENS * 512 * 4);
    float* lse     = (float*)alloc((size_t)TOKENS * 4);
    float* tlg     = (float*)alloc((size_t)TOKENS * 4);
    (void)ws_size; (void)in_sizes; (void)n_in; (void)out_size;

    // weight conversions + embedding gather
    k_cvt_bf16<<<dim3((G3 * DIM / 8 + 255) / 256), dim3(256), 0, stream>>>(W_ih, Wihb, G3 * DIM / 8);
    k_cvt_bf16<<<dim3((G3 * HID / 8 + 255) / 256), dim3(256), 0, stream>>>(W_hh, Whhb, G3 * HID / 8);
    k_cvt_bf16<<<dim3((VOCAB * DIM / 8 + 255) / 256), dim3(256), 0, stream>>>(W_out, Woutb, VOCAB * DIM / 8);
    k_gather_x<<<dim3(TOKENS * DIM / 8 / 256), dim3(256), 0, stream>>>(word_emb, review_input, Xb);

    // GI = X @ W_ih^T + b_ih
    k_gemm_gi<<<dim3(TOKENS / 64, G3 / 64), dim3(256), 0, stream>>>(Xb, Wihb, b_ih, GI);

    // GRU recurrence: 50 per-step kernels (proven 4.5 us/step)
    hipMemsetAsync(hf, 0, (size_t)BATCH * HID * 4, stream);
    hipMemsetAsync(hzero, 0, (size_t)BATCH * HID * 2, stream);
    for (int s = 0; s < S_LEN; ++s) {
        const unsigned short* hin = s ? (HS + (size_t)(s - 1) * BATCH * HID) : hzero;
        unsigned short* hout = HS + (size_t)s * BATCH * HID;
        k_gru_step<<<dim3(128), dim3(128), 0, stream>>>(GI, Whhb, b_hh, hf, hin, hout, s);
    }

    // decode: partial exp-sums, reduce to lse, target logits, final loss
    k_decode<<<dim3(NWG), dim3(1024), 0, stream>>>(HS, Woutb, b_out, partial);
    k_reduce_lse<<<dim3(TOKENS / 4), dim3(256), 0, stream>>>(partial, lse);
    k_tlogit<<<dim3(TOKENS / 4), dim3(256), 0, stream>>>(HS, Woutb, b_out, review_target, tlg);
    k_finalize<<<dim3(1), dim3(256), 0, stream>>>(lse, tlg, review_target, out);
}

// Round 10
// 538.103 us; speedup vs baseline: 2.1478x; 1.1713x over previous
//
#include <hip/hip_runtime.h>
#include <hip/hip_bf16.h>

typedef __attribute__((ext_vector_type(8))) short short8;
typedef __attribute__((ext_vector_type(4))) float floatx4;

#define S_LEN  50
#define BATCH  128
#define DIM    512
#define HID    512
#define G3     1536
#define VOCAB  30000
#define TOKENS 6400
#define NB256  118      // ceil(30000/256) vocab chunks in decode
#define NVC    472      // partial columns = NB256 * 4 waves
#define NWG    (25 * NB256)   // 2950 decode blocks

__device__ __forceinline__ float bf2f(short u) {
    union { unsigned int i; float f; } c;
    c.i = ((unsigned int)(unsigned short)u) << 16;
    return c.f;
}
__device__ __forceinline__ unsigned short f2bf(float x) {
    __hip_bfloat16 h = __float2bfloat16(x);
    unsigned short u;
    __builtin_memcpy(&u, &h, 2);
    return u;
}

// ---------------- f32 -> bf16 bulk convert (8 elems/thread) ----------------
__global__ void k_cvt_bf16(const float* __restrict__ src,
                           unsigned short* __restrict__ dst, int n8) {
    int g = blockIdx.x * 256 + threadIdx.x;
    if (g >= n8) return;
    const float* s = src + (size_t)g * 8;
    union { short8 v; unsigned short u[8]; } o;
#pragma unroll
    for (int i = 0; i < 8; ++i) o.u[i] = f2bf(s[i]);
    *(short8*)(dst + (size_t)g * 8) = o.v;
}

// ---------------- embedding gather + convert: X[token][512] bf16 ----------------
__global__ void k_gather_x(const float* __restrict__ emb, const int* __restrict__ idx,
                           unsigned short* __restrict__ X) {
    int g = blockIdx.x * 256 + threadIdx.x;   // 8-elem group; total TOKENS*DIM/8
    int token = g >> 6;                       // 64 groups per token
    int chunk = (g & 63) << 3;
    const float* src = emb + (size_t)idx[token] * DIM + chunk;
    union { short8 v; unsigned short u[8]; } o;
#pragma unroll
    for (int i = 0; i < 8; ++i) o.u[i] = f2bf(src[i]);
    *(short8*)(X + (size_t)token * DIM + chunk) = o.v;
}

// ---------------- GI = X @ W_ih^T + b_ih   [6400 x 1536] fp32 ----------------
__launch_bounds__(256)
__global__ void k_gemm_gi(const unsigned short* __restrict__ X,
                          const unsigned short* __restrict__ Wih,
                          const float* __restrict__ b_ih,
                          float* __restrict__ GI) {
    __shared__ unsigned short As[64][72];
    __shared__ unsigned short Bs[64][72];
    int m0 = blockIdx.x * 64;
    int n0 = blockIdx.y * 64;
    int t = threadIdx.x;
    int w = t >> 6, lane = t & 63;
    floatx4 zero = {0.f, 0.f, 0.f, 0.f};
    floatx4 acc[4];
#pragma unroll
    for (int i = 0; i < 4; ++i) acc[i] = zero;
    int srow = t >> 2, scol = (t & 3) * 16;
    for (int k0 = 0; k0 < DIM; k0 += 64) {
        *(short8*)&As[srow][scol]     = *(const short8*)(X   + (size_t)(m0 + srow) * DIM + k0 + scol);
        *(short8*)&As[srow][scol + 8] = *(const short8*)(X   + (size_t)(m0 + srow) * DIM + k0 + scol + 8);
        *(short8*)&Bs[srow][scol]     = *(const short8*)(Wih + (size_t)(n0 + srow) * DIM + k0 + scol);
        *(short8*)&Bs[srow][scol + 8] = *(const short8*)(Wih + (size_t)(n0 + srow) * DIM + k0 + scol + 8);
        __syncthreads();
#pragma unroll
        for (int kt = 0; kt < 2; ++kt) {
            short8 a = *(const short8*)&As[w * 16 + (lane & 15)][kt * 32 + (lane >> 4) * 8];
#pragma unroll
            for (int nt = 0; nt < 4; ++nt) {
                short8 b = *(const short8*)&Bs[nt * 16 + (lane & 15)][kt * 32 + (lane >> 4) * 8];
                acc[nt] = __builtin_amdgcn_mfma_f32_16x16x32_bf16(a, b, acc[nt], 0, 0, 0);
            }
        }
        __syncthreads();
    }
#pragma unroll
    for (int nt = 0; nt < 4; ++nt)
#pragma unroll
        for (int r = 0; r < 4; ++r) {
            int row = m0 + w * 16 + (lane >> 4) * 4 + r;
            int col = n0 + nt * 16 + (lane & 15);
            GI[(size_t)row * G3 + col] = acc[nt][r] + b_ih[col];
        }
}

// ---------------- GRU single step: 256 blocks x 64 thr (all CUs) ----------------
// Block = (batch group bg of 16 rows) x (hidden slice hs of 16 units), 1 wave.
// Same per-lane math/order as the proven round-5 kernel, just 2x more blocks.
__launch_bounds__(64)
__global__ void k_gru_step(const float* __restrict__ GI,
                           const unsigned short* __restrict__ Whh,
                           const float* __restrict__ b_hh,
                           float* __restrict__ hf,
                           const unsigned short* __restrict__ hin,
                           unsigned short* __restrict__ hout,
                           int s) {
    int lane = threadIdx.x & 63;
    int bg = blockIdx.x & 7;      // batch group (8 groups of 16)
    int hs = blockIdx.x >> 3;     // hidden slice (32 slices of 16)
    int jc = hs * 16 + (lane & 15);   // hidden unit (N index)

    const unsigned short* pa  = hin + (size_t)(bg * 16 + (lane & 15)) * HID + (lane >> 4) * 8;
    const unsigned short* pb0 = Whh + (size_t)(0 * HID + jc) * DIM + (lane >> 4) * 8;
    const unsigned short* pb1 = Whh + (size_t)(1 * HID + jc) * DIM + (lane >> 4) * 8;
    const unsigned short* pb2 = Whh + (size_t)(2 * HID + jc) * DIM + (lane >> 4) * 8;

    floatx4 acc0 = {0.f, 0.f, 0.f, 0.f};
    floatx4 acc1 = {0.f, 0.f, 0.f, 0.f};
    floatx4 acc2 = {0.f, 0.f, 0.f, 0.f};
#pragma unroll
    for (int kt = 0; kt < 16; ++kt) {
        short8 a = *(const short8*)(pa + kt * 32);
        acc0 = __builtin_amdgcn_mfma_f32_16x16x32_bf16(a, *(const short8*)(pb0 + kt * 32), acc0, 0, 0, 0);
        acc1 = __builtin_amdgcn_mfma_f32_16x16x32_bf16(a, *(const short8*)(pb1 + kt * 32), acc1, 0, 0, 0);
        acc2 = __builtin_amdgcn_mfma_f32_16x16x32_bf16(a, *(const short8*)(pb2 + kt * 32), acc2, 0, 0, 0);
    }
    float bhr = b_hh[jc], bhz = b_hh[jc + 512], bhn = b_hh[jc + 1024];
#pragma unroll
    for (int r = 0; r < 4; ++r) {
        int brow = bg * 16 + (lane >> 4) * 4 + r;   // batch row (M index)
        int tok = s * BATCH + brow;
        const float* gi = GI + (size_t)tok * G3;
        float rg = 1.f / (1.f + __expf(-(gi[jc] + acc0[r] + bhr)));
        float zg = 1.f / (1.f + __expf(-(gi[jc + 512] + acc1[r] + bhz)));
        float ng = tanhf(gi[jc + 1024] + rg * (acc2[r] + bhn));
        size_t hidx = (size_t)brow * HID + jc;
        float hn = (1.f - zg) * ng + zg * hf[hidx];
        hf[hidx] = hn;
        hout[hidx] = f2bf(hn);
    }
}

// ---------------- decode: 256x256 tile, 16 waves (4x4), XOR-swizzled LDS ----------------
// Block order: supergroups of 8 nb x 25 mb (mb-major inner) so each XCD's L2
// keeps an ~2 MB B-set resident while A streams; bijective XCD chunking on top.
__launch_bounds__(1024, 4)
__global__ void k_decode(const unsigned short* __restrict__ HS,
                         const unsigned short* __restrict__ Wout,
                         const float* __restrict__ b_out,
                         float* __restrict__ partial) {
    __shared__ unsigned short As[256 * 64];
    __shared__ unsigned short Bs[256 * 64];

    // bijective XCD chunk swizzle (nwg=2950, q=368, r=6)
    int bid = blockIdx.x;
    int xcd = bid & 7, pos = bid >> 3;
    int p = (xcd < 6 ? xcd * 369 : 2214 + (xcd - 6) * 368) + pos;
    // supergroup order: 14 groups of 8 nb + 1 group of 6 nb; mb-major within group
    int sgrp = p / 200;             // 25 mb * 8 nb = 200 blocks per full group
    int rr   = p - sgrp * 200;
    int mb, nb;
    if (sgrp < 14) { mb = rr >> 3; nb = sgrp * 8 + (rr & 7); }
    else           { int q6 = rr / 6; mb = q6; nb = 112 + (rr - q6 * 6); }
    int m0 = mb * 256, n0 = nb * 256;

    int t = threadIdx.x, w = t >> 6, lane = t & 63;
    int wr = w >> 2, wc = w & 3;            // 4x4 wave grid

    floatx4 zero = {0.f, 0.f, 0.f, 0.f};
    floatx4 acc[4][4];
#pragma unroll
    for (int mi = 0; mi < 4; ++mi)
#pragma unroll
        for (int ni = 0; ni < 4; ++ni) acc[mi][ni] = zero;

    // staging: thread t owns row t>>2 (0..255), 32B chunk (t&3)
    int srow = t >> 2;
    int scb  = (t & 3) * 32;                // byte offset of 32B chunk within row
    int swz  = (srow & 7) << 4;
    const unsigned short* gA = HS + (size_t)(m0 + srow) * DIM + (t & 3) * 16;
    int vrow = n0 + srow; if (vrow > VOCAB - 1) vrow = VOCAB - 1;
    const unsigned short* gB = Wout + (size_t)vrow * DIM + (t & 3) * 16;
    char* wA0 = (char*)As + ((srow * 128 + scb)      ^ swz);
    char* wA1 = (char*)As + ((srow * 128 + scb + 16) ^ swz);
    char* wB0 = (char*)Bs + ((srow * 128 + scb)      ^ swz);
    char* wB1 = (char*)Bs + ((srow * 128 + scb + 16) ^ swz);

    for (int k0 = 0; k0 < DIM; k0 += 64) {
        short8 a0 = *(const short8*)(gA + k0);
        short8 a1 = *(const short8*)(gA + k0 + 8);
        short8 b0 = *(const short8*)(gB + k0);
        short8 b1 = *(const short8*)(gB + k0 + 8);
        *(short8*)wA0 = a0;
        *(short8*)wA1 = a1;
        *(short8*)wB0 = b0;
        *(short8*)wB1 = b1;
        __syncthreads();
#pragma unroll
        for (int kt = 0; kt < 2; ++kt) {
            short8 af[4], bf[4];
#pragma unroll
            for (int mi = 0; mi < 4; ++mi) {
                int row = wr * 64 + mi * 16 + (lane & 15);
                int off = (row * 128 + kt * 64 + (lane >> 4) * 16) ^ ((row & 7) << 4);
                af[mi] = *(const short8*)((const char*)As + off);
            }
#pragma unroll
            for (int ni = 0; ni < 4; ++ni) {
                int row = wc * 64 + ni * 16 + (lane & 15);
                int off = (row * 128 + kt * 64 + (lane >> 4) * 16) ^ ((row & 7) << 4);
                bf[ni] = *(const short8*)((const char*)Bs + off);
            }
#pragma unroll
            for (int mi = 0; mi < 4; ++mi)
#pragma unroll
                for (int ni = 0; ni < 4; ++ni)
                    acc[mi][ni] = __builtin_amdgcn_mfma_f32_16x16x32_bf16(af[mi], bf[ni], acc[mi][ni], 0, 0, 0);
        }
        __syncthreads();
    }

    // epilogue: exp + per-token partial sums over this wave's 64 vocab cols
    float esum[4][4];   // [mi][r]
#pragma unroll
    for (int mi = 0; mi < 4; ++mi)
#pragma unroll
        for (int r = 0; r < 4; ++r) esum[mi][r] = 0.f;
#pragma unroll
    for (int ni = 0; ni < 4; ++ni) {
        int v = n0 + wc * 64 + ni * 16 + (lane & 15);
        bool ok = v < VOCAB;
        float bo = ok ? b_out[v] : 0.f;
#pragma unroll
        for (int mi = 0; mi < 4; ++mi)
#pragma unroll
            for (int r = 0; r < 4; ++r) {
                float logit = acc[mi][ni][r] + bo;
                esum[mi][r] += ok ? __expf(logit) : 0.f;
            }
    }
#pragma unroll
    for (int d = 1; d < 16; d <<= 1)
#pragma unroll
        for (int mi = 0; mi < 4; ++mi)
#pragma unroll
            for (int r = 0; r < 4; ++r) esum[mi][r] += __shfl_xor(esum[mi][r], d, 64);
    if ((lane & 15) == 0) {
#pragma unroll
        for (int mi = 0; mi < 4; ++mi)
#pragma unroll
            for (int r = 0; r < 4; ++r) {
                int tok = m0 + wr * 64 + mi * 16 + (lane >> 4) * 4 + r;
                partial[(size_t)tok * 512 + nb * 4 + wc] = esum[mi][r];
            }
    }
}

// ---------------- fixed-order reduce of partials -> lse ----------------
__global__ void k_reduce_lse(const float* __restrict__ partial, float* __restrict__ lse) {
    int tok = blockIdx.x * 4 + (threadIdx.x >> 6);
    int lane = threadIdx.x & 63;
    float s = 0.f;
    for (int j = lane; j < NVC; j += 64) s += partial[(size_t)tok * 512 + j];
#pragma unroll
    for (int d = 1; d < 64; d <<= 1) s += __shfl_xor(s, d, 64);
    if (lane == 0) lse[tok] = logf(s);
}

// ---------------- target logit: one wave per token ----------------
__global__ void k_tlogit(const unsigned short* __restrict__ HS,
                         const unsigned short* __restrict__ Wout,
                         const float* __restrict__ b_out,
                         const int* __restrict__ target,
                         float* __restrict__ tlg) {
    int tok = blockIdx.x * 4 + (threadIdx.x >> 6);
    int lane = threadIdx.x & 63;
    int tg = target[tok];
    short8 a = *(const short8*)(HS + (size_t)tok * DIM + lane * 8);
    short8 b = *(const short8*)(Wout + (size_t)tg * DIM + lane * 8);
    float s = 0.f;
#pragma unroll
    for (int i = 0; i < 8; ++i) s += bf2f(a[i]) * bf2f(b[i]);
#pragma unroll
    for (int d = 1; d < 64; d <<= 1) s += __shfl_xor(s, d, 64);
    if (lane == 0) tlg[tok] = s + b_out[tg];
}

// ---------------- loss + masked mean ----------------
__global__ void k_finalize(const float* __restrict__ lse, const float* __restrict__ tlg,
                           const int* __restrict__ target, float* __restrict__ out) {
    __shared__ float ssum[256];
    __shared__ float scnt[256];
    int t = threadIdx.x;
    float ls = 0.f, lc = 0.f;
    for (int i = t; i < TOKENS; i += 256) {
        int tg = target[i];
        float loss = (tg != 0) ? (lse[i] - tlg[i]) : 0.f;
        out[i] = loss;
        ls += loss;
        lc += (tg != 0) ? 1.f : 0.f;
    }
    ssum[t] = ls; scnt[t] = lc;
    __syncthreads();
    for (int d = 128; d > 0; d >>= 1) {
        if (t < d) { ssum[t] += ssum[t + d]; scnt[t] += scnt[t + d]; }
        __syncthreads();
    }
    if (t == 0) out[TOKENS] = ssum[0] / fmaxf(scnt[0], 1.f);
}

extern "C" void kernel_launch(void* const* d_in, const int* in_sizes, int n_in,
                              void* d_out, int out_size, void* d_ws, size_t ws_size,
                              hipStream_t stream) {
    const int*   review_input  = (const int*)d_in[2];
    const int*   review_target = (const int*)d_in[3];
    const float* word_emb      = (const float*)d_in[4];
    const float* W_ih          = (const float*)d_in[5];
    const float* W_hh          = (const float*)d_in[6];
    const float* b_ih          = (const float*)d_in[7];
    const float* b_hh          = (const float*)d_in[8];
    const float* W_out         = (const float*)d_in[9];
    const float* b_out         = (const float*)d_in[10];
    float* out = (float*)d_out;

    char* ws = (char*)d_ws;
    size_t off = 0;
    auto alloc = [&](size_t n) { char* p = ws + off; off += (n + 255) & ~(size_t)255; return p; };
    unsigned short* Xb    = (unsigned short*)alloc((size_t)TOKENS * DIM * 2);
    unsigned short* Wihb  = (unsigned short*)alloc((size_t)G3 * DIM * 2);
    unsigned short* Whhb  = (unsigned short*)alloc((size_t)G3 * HID * 2);
    unsigned short* Woutb = (unsigned short*)alloc((size_t)VOCAB * DIM * 2);
    unsigned short* HS    = (unsigned short*)alloc((size_t)TOKENS * HID * 2);
    unsigned short* hzero = (unsigned short*)alloc((size_t)BATCH * HID * 2);
    float* hf      = (float*)alloc((size_t)BATCH * HID * 4);
    float* GI      = (float*)alloc((size_t)TOKENS * G3 * 4);
    float* partial = (float*)alloc((size_t)TOKENS * 512 * 4);
    float* lse     = (float*)alloc((size_t)TOKENS * 4);
    float* tlg     = (float*)alloc((size_t)TOKENS * 4);
    (void)ws_size; (void)in_sizes; (void)n_in; (void)out_size;

    // weight conversions + embedding gather
    k_cvt_bf16<<<dim3((G3 * DIM / 8 + 255) / 256), dim3(256), 0, stream>>>(W_ih, Wihb, G3 * DIM / 8);
    k_cvt_bf16<<<dim3((G3 * HID / 8 + 255) / 256), dim3(256), 0, stream>>>(W_hh, Whhb, G3 * HID / 8);
    k_cvt_bf16<<<dim3((VOCAB * DIM / 8 + 255) / 256), dim3(256), 0, stream>>>(W_out, Woutb, VOCAB * DIM / 8);
    k_gather_x<<<dim3(TOKENS * DIM / 8 / 256), dim3(256), 0, stream>>>(word_emb, review_input, Xb);

    // GI = X @ W_ih^T + b_ih
    k_gemm_gi<<<dim3(TOKENS / 64, G3 / 64), dim3(256), 0, stream>>>(Xb, Wihb, b_ih, GI);

    // GRU recurrence: 50 per-step kernels, 256 blocks x 64 thr (all CUs)
    hipMemsetAsync(hf, 0, (size_t)BATCH * HID * 4, stream);
    hipMemsetAsync(hzero, 0, (size_t)BATCH * HID * 2, stream);
    for (int s = 0; s < S_LEN; ++s) {
        const unsigned short* hin = s ? (HS + (size_t)(s - 1) * BATCH * HID) : hzero;
        unsigned short* hout = HS + (size_t)s * BATCH * HID;
        k_gru_step<<<dim3(256), dim3(64), 0, stream>>>(GI, Whhb, b_hh, hf, hin, hout, s);
    }

    // decode: partial exp-sums, reduce to lse, target logits, final loss
    k_decode<<<dim3(NWG), dim3(1024), 0, stream>>>(HS, Woutb, b_out, partial);
    k_reduce_lse<<<dim3(TOKENS / 4), dim3(256), 0, stream>>>(partial, lse);
    k_tlogit<<<dim3(TOKENS / 4), dim3(256), 0, stream>>>(HS, Woutb, b_out, review_target, tlg);
    k_finalize<<<dim3(1), dim3(256), 0, stream>>>(lse, tlg, review_target, out);
}

// Round 11
// 530.947 us; speedup vs baseline: 2.1768x; 1.0135x over previous
//
#include <hip/hip_runtime.h>
#include <hip/hip_bf16.h>

typedef __attribute__((ext_vector_type(8))) short short8;
typedef __attribute__((ext_vector_type(4))) float floatx4;

#define S_LEN  50
#define BATCH  128
#define DIM    512
#define HID    512
#define G3     1536
#define VOCAB  30000
#define TOKENS 6400
#define NB256  118      // ceil(30000/256) vocab chunks in decode
#define NVC    472      // partial columns = NB256 * 4 waves
#define NWG    (25 * NB256)   // 2950 decode blocks

__device__ __forceinline__ float bf2f(short u) {
    union { unsigned int i; float f; } c;
    c.i = ((unsigned int)(unsigned short)u) << 16;
    return c.f;
}
__device__ __forceinline__ unsigned short f2bf(float x) {
    __hip_bfloat16 h = __float2bfloat16(x);
    unsigned short u;
    __builtin_memcpy(&u, &h, 2);
    return u;
}

// ---------------- f32 -> bf16 bulk convert (8 elems/thread) ----------------
__global__ void k_cvt_bf16(const float* __restrict__ src,
                           unsigned short* __restrict__ dst, int n8) {
    int g = blockIdx.x * 256 + threadIdx.x;
    if (g >= n8) return;
    const float* s = src + (size_t)g * 8;
    union { short8 v; unsigned short u[8]; } o;
#pragma unroll
    for (int i = 0; i < 8; ++i) o.u[i] = f2bf(s[i]);
    *(short8*)(dst + (size_t)g * 8) = o.v;
}

// ---------------- embedding gather + convert: X[token][512] bf16 ----------------
__global__ void k_gather_x(const float* __restrict__ emb, const int* __restrict__ idx,
                           unsigned short* __restrict__ X) {
    int g = blockIdx.x * 256 + threadIdx.x;   // 8-elem group; total TOKENS*DIM/8
    int token = g >> 6;                       // 64 groups per token
    int chunk = (g & 63) << 3;
    const float* src = emb + (size_t)idx[token] * DIM + chunk;
    union { short8 v; unsigned short u[8]; } o;
#pragma unroll
    for (int i = 0; i < 8; ++i) o.u[i] = f2bf(src[i]);
    *(short8*)(X + (size_t)token * DIM + chunk) = o.v;
}

// ---------------- GI = X @ W_ih^T + b_ih   [6400 x 1536] fp32 ----------------
__launch_bounds__(256)
__global__ void k_gemm_gi(const unsigned short* __restrict__ X,
                          const unsigned short* __restrict__ Wih,
                          const float* __restrict__ b_ih,
                          float* __restrict__ GI) {
    __shared__ unsigned short As[64][72];
    __shared__ unsigned short Bs[64][72];
    int m0 = blockIdx.x * 64;
    int n0 = blockIdx.y * 64;
    int t = threadIdx.x;
    int w = t >> 6, lane = t & 63;
    floatx4 zero = {0.f, 0.f, 0.f, 0.f};
    floatx4 acc[4];
#pragma unroll
    for (int i = 0; i < 4; ++i) acc[i] = zero;
    int srow = t >> 2, scol = (t & 3) * 16;
    for (int k0 = 0; k0 < DIM; k0 += 64) {
        *(short8*)&As[srow][scol]     = *(const short8*)(X   + (size_t)(m0 + srow) * DIM + k0 + scol);
        *(short8*)&As[srow][scol + 8] = *(const short8*)(X   + (size_t)(m0 + srow) * DIM + k0 + scol + 8);
        *(short8*)&Bs[srow][scol]     = *(const short8*)(Wih + (size_t)(n0 + srow) * DIM + k0 + scol);
        *(short8*)&Bs[srow][scol + 8] = *(const short8*)(Wih + (size_t)(n0 + srow) * DIM + k0 + scol + 8);
        __syncthreads();
#pragma unroll
        for (int kt = 0; kt < 2; ++kt) {
            short8 a = *(const short8*)&As[w * 16 + (lane & 15)][kt * 32 + (lane >> 4) * 8];
#pragma unroll
            for (int nt = 0; nt < 4; ++nt) {
                short8 b = *(const short8*)&Bs[nt * 16 + (lane & 15)][kt * 32 + (lane >> 4) * 8];
                acc[nt] = __builtin_amdgcn_mfma_f32_16x16x32_bf16(a, b, acc[nt], 0, 0, 0);
            }
        }
        __syncthreads();
    }
#pragma unroll
    for (int nt = 0; nt < 4; ++nt)
#pragma unroll
        for (int r = 0; r < 4; ++r) {
            int row = m0 + w * 16 + (lane >> 4) * 4 + r;
            int col = n0 + nt * 16 + (lane & 15);
            GI[(size_t)row * G3 + col] = acc[nt][r] + b_ih[col];
        }
}

// ---------------- GRU single step: 256 blocks x 64 thr (all CUs) ----------------
__launch_bounds__(64)
__global__ void k_gru_step(const float* __restrict__ GI,
                           const unsigned short* __restrict__ Whh,
                           const float* __restrict__ b_hh,
                           float* __restrict__ hf,
                           const unsigned short* __restrict__ hin,
                           unsigned short* __restrict__ hout,
                           int s) {
    int lane = threadIdx.x & 63;
    int bg = blockIdx.x & 7;      // batch group (8 groups of 16)
    int hs = blockIdx.x >> 3;     // hidden slice (32 slices of 16)
    int jc = hs * 16 + (lane & 15);   // hidden unit (N index)

    const unsigned short* pa  = hin + (size_t)(bg * 16 + (lane & 15)) * HID + (lane >> 4) * 8;
    const unsigned short* pb0 = Whh + (size_t)(0 * HID + jc) * DIM + (lane >> 4) * 8;
    const unsigned short* pb1 = Whh + (size_t)(1 * HID + jc) * DIM + (lane >> 4) * 8;
    const unsigned short* pb2 = Whh + (size_t)(2 * HID + jc) * DIM + (lane >> 4) * 8;

    floatx4 acc0 = {0.f, 0.f, 0.f, 0.f};
    floatx4 acc1 = {0.f, 0.f, 0.f, 0.f};
    floatx4 acc2 = {0.f, 0.f, 0.f, 0.f};
#pragma unroll
    for (int kt = 0; kt < 16; ++kt) {
        short8 a = *(const short8*)(pa + kt * 32);
        acc0 = __builtin_amdgcn_mfma_f32_16x16x32_bf16(a, *(const short8*)(pb0 + kt * 32), acc0, 0, 0, 0);
        acc1 = __builtin_amdgcn_mfma_f32_16x16x32_bf16(a, *(const short8*)(pb1 + kt * 32), acc1, 0, 0, 0);
        acc2 = __builtin_amdgcn_mfma_f32_16x16x32_bf16(a, *(const short8*)(pb2 + kt * 32), acc2, 0, 0, 0);
    }
    float bhr = b_hh[jc], bhz = b_hh[jc + 512], bhn = b_hh[jc + 1024];
#pragma unroll
    for (int r = 0; r < 4; ++r) {
        int brow = bg * 16 + (lane >> 4) * 4 + r;   // batch row (M index)
        int tok = s * BATCH + brow;
        const float* gi = GI + (size_t)tok * G3;
        float rg = 1.f / (1.f + __expf(-(gi[jc] + acc0[r] + bhr)));
        float zg = 1.f / (1.f + __expf(-(gi[jc + 512] + acc1[r] + bhz)));
        float ng = tanhf(gi[jc + 1024] + rg * (acc2[r] + bhn));
        size_t hidx = (size_t)brow * HID + jc;
        float hn = (1.f - zg) * ng + zg * hf[hidx];
        hf[hidx] = hn;
        hout[hidx] = f2bf(hn);
    }
}

// ---------------- decode: 256x256 tile, dbuf LDS, 1 barrier/K-iter ----------------
// 16 waves (4x4), each a 64x64 quadrant. BK=64, 8 K-iters. LDS 2x64=128 KB.
// Per iter: issue next tile's global loads (latency hides under MFMA), MFMA on
// buf[cur], ds_write staged regs to buf[cur^1], ONE __syncthreads.
__launch_bounds__(1024, 4)
__global__ void k_decode(const unsigned short* __restrict__ HS,
                         const unsigned short* __restrict__ Wout,
                         const float* __restrict__ b_out,
                         float* __restrict__ partial) {
    __shared__ unsigned short As[2][256 * 64];
    __shared__ unsigned short Bs[2][256 * 64];

    // bijective XCD chunk swizzle (nwg=2950, q=368, r=6)
    int bid = blockIdx.x;
    int xcd = bid & 7, pos = bid >> 3;
    int p = (xcd < 6 ? xcd * 369 : 2214 + (xcd - 6) * 368) + pos;
    // supergroup order: 14 groups of 8 nb + 1 group of 6 nb; mb-major within group
    int sgrp = p / 200;             // 25 mb * 8 nb = 200 blocks per full group
    int rr   = p - sgrp * 200;
    int mb, nb;
    if (sgrp < 14) { mb = rr >> 3; nb = sgrp * 8 + (rr & 7); }
    else           { int q6 = rr / 6; mb = q6; nb = 112 + (rr - q6 * 6); }
    int m0 = mb * 256, n0 = nb * 256;

    int t = threadIdx.x, w = t >> 6, lane = t & 63;
    int wr = w >> 2, wc = w & 3;            // 4x4 wave grid

    floatx4 zero = {0.f, 0.f, 0.f, 0.f};
    floatx4 acc[4][4];
#pragma unroll
    for (int mi = 0; mi < 4; ++mi)
#pragma unroll
        for (int ni = 0; ni < 4; ++ni) acc[mi][ni] = zero;

    // staging: thread t owns row t>>2 (0..255), 32B chunk (t&3)
    int srow = t >> 2;
    int scb  = (t & 3) * 32;                // byte offset of 32B chunk within row
    int swz  = (srow & 7) << 4;
    const unsigned short* gA = HS + (size_t)(m0 + srow) * DIM + (t & 3) * 16;
    int vrow = n0 + srow; if (vrow > VOCAB - 1) vrow = VOCAB - 1;
    const unsigned short* gB = Wout + (size_t)vrow * DIM + (t & 3) * 16;
    int wo0 = (srow * 128 + scb)      ^ swz;   // swizzled write offsets (bytes)
    int wo1 = (srow * 128 + scb + 16) ^ swz;

    // read offsets (bytes) per wave fragment
    int roA[4][2], roB[4][2];
#pragma unroll
    for (int mi = 0; mi < 4; ++mi)
#pragma unroll
        for (int kt = 0; kt < 2; ++kt) {
            int row = wr * 64 + mi * 16 + (lane & 15);
            roA[mi][kt] = (row * 128 + kt * 64 + (lane >> 4) * 16) ^ ((row & 7) << 4);
        }
#pragma unroll
    for (int ni = 0; ni < 4; ++ni)
#pragma unroll
        for (int kt = 0; kt < 2; ++kt) {
            int row = wc * 64 + ni * 16 + (lane & 15);
            roB[ni][kt] = (row * 128 + kt * 64 + (lane >> 4) * 16) ^ ((row & 7) << 4);
        }

    // prologue: stage tile 0 into buf 0
    {
        short8 a0 = *(const short8*)(gA);
        short8 a1 = *(const short8*)(gA + 8);
        short8 b0 = *(const short8*)(gB);
        short8 b1 = *(const short8*)(gB + 8);
        *(short8*)((char*)As[0] + wo0) = a0;
        *(short8*)((char*)As[0] + wo1) = a1;
        *(short8*)((char*)Bs[0] + wo0) = b0;
        *(short8*)((char*)Bs[0] + wo1) = b1;
    }
    __syncthreads();

    for (int ki = 0; ki < 8; ++ki) {
        int cur = ki & 1;
        short8 a0, a1, b0, b1;
        if (ki < 7) {                        // issue next-tile loads early
            int k0 = (ki + 1) * 64;
            a0 = *(const short8*)(gA + k0);
            a1 = *(const short8*)(gA + k0 + 8);
            b0 = *(const short8*)(gB + k0);
            b1 = *(const short8*)(gB + k0 + 8);
        }
#pragma unroll
        for (int kt = 0; kt < 2; ++kt) {
            short8 af[4], bf[4];
#pragma unroll
            for (int mi = 0; mi < 4; ++mi)
                af[mi] = *(const short8*)((const char*)As[cur] + roA[mi][kt]);
#pragma unroll
            for (int ni = 0; ni < 4; ++ni)
                bf[ni] = *(const short8*)((const char*)Bs[cur] + roB[ni][kt]);
#pragma unroll
            for (int mi = 0; mi < 4; ++mi)
#pragma unroll
                for (int ni = 0; ni < 4; ++ni)
                    acc[mi][ni] = __builtin_amdgcn_mfma_f32_16x16x32_bf16(af[mi], bf[ni], acc[mi][ni], 0, 0, 0);
        }
        if (ki < 7) {                        // write staged tile to other buffer
            int nxt = cur ^ 1;
            *(short8*)((char*)As[nxt] + wo0) = a0;
            *(short8*)((char*)As[nxt] + wo1) = a1;
            *(short8*)((char*)Bs[nxt] + wo0) = b0;
            *(short8*)((char*)Bs[nxt] + wo1) = b1;
        }
        __syncthreads();                     // single barrier per K-iter
    }

    // epilogue: exp + per-token partial sums over this wave's 64 vocab cols
    float esum[4][4];   // [mi][r]
#pragma unroll
    for (int mi = 0; mi < 4; ++mi)
#pragma unroll
        for (int r = 0; r < 4; ++r) esum[mi][r] = 0.f;
#pragma unroll
    for (int ni = 0; ni < 4; ++ni) {
        int v = n0 + wc * 64 + ni * 16 + (lane & 15);
        bool ok = v < VOCAB;
        float bo = ok ? b_out[v] : 0.f;
#pragma unroll
        for (int mi = 0; mi < 4; ++mi)
#pragma unroll
            for (int r = 0; r < 4; ++r) {
                float logit = acc[mi][ni][r] + bo;
                esum[mi][r] += ok ? __expf(logit) : 0.f;
            }
    }
#pragma unroll
    for (int d = 1; d < 16; d <<= 1)
#pragma unroll
        for (int mi = 0; mi < 4; ++mi)
#pragma unroll
            for (int r = 0; r < 4; ++r) esum[mi][r] += __shfl_xor(esum[mi][r], d, 64);
    if ((lane & 15) == 0) {
#pragma unroll
        for (int mi = 0; mi < 4; ++mi)
#pragma unroll
            for (int r = 0; r < 4; ++r) {
                int tok = m0 + wr * 64 + mi * 16 + (lane >> 4) * 4 + r;
                partial[(size_t)tok * 512 + nb * 4 + wc] = esum[mi][r];
            }
    }
}

// ---------------- fixed-order reduce of partials -> lse ----------------
__global__ void k_reduce_lse(const float* __restrict__ partial, float* __restrict__ lse) {
    int tok = blockIdx.x * 4 + (threadIdx.x >> 6);
    int lane = threadIdx.x & 63;
    float s = 0.f;
    for (int j = lane; j < NVC; j += 64) s += partial[(size_t)tok * 512 + j];
#pragma unroll
    for (int d = 1; d < 64; d <<= 1) s += __shfl_xor(s, d, 64);
    if (lane == 0) lse[tok] = logf(s);
}

// ---------------- target logit: one wave per token ----------------
__global__ void k_tlogit(const unsigned short* __restrict__ HS,
                         const unsigned short* __restrict__ Wout,
                         const float* __restrict__ b_out,
                         const int* __restrict__ target,
                         float* __restrict__ tlg) {
    int tok = blockIdx.x * 4 + (threadIdx.x >> 6);
    int lane = threadIdx.x & 63;
    int tg = target[tok];
    short8 a = *(const short8*)(HS + (size_t)tok * DIM + lane * 8);
    short8 b = *(const short8*)(Wout + (size_t)tg * DIM + lane * 8);
    float s = 0.f;
#pragma unroll
    for (int i = 0; i < 8; ++i) s += bf2f(a[i]) * bf2f(b[i]);
#pragma unroll
    for (int d = 1; d < 64; d <<= 1) s += __shfl_xor(s, d, 64);
    if (lane == 0) tlg[tok] = s + b_out[tg];
}

// ---------------- loss + masked mean ----------------
__global__ void k_finalize(const float* __restrict__ lse, const float* __restrict__ tlg,
                           const int* __restrict__ target, float* __restrict__ out) {
    __shared__ float ssum[256];
    __shared__ float scnt[256];
    int t = threadIdx.x;
    float ls = 0.f, lc = 0.f;
    for (int i = t; i < TOKENS; i += 256) {
        int tg = target[i];
        float loss = (tg != 0) ? (lse[i] - tlg[i]) : 0.f;
        out[i] = loss;
        ls += loss;
        lc += (tg != 0) ? 1.f : 0.f;
    }
    ssum[t] = ls; scnt[t] = lc;
    __syncthreads();
    for (int d = 128; d > 0; d >>= 1) {
        if (t < d) { ssum[t] += ssum[t + d]; scnt[t] += scnt[t + d]; }
        __syncthreads();
    }
    if (t == 0) out[TOKENS] = ssum[0] / fmaxf(scnt[0], 1.f);
}

extern "C" void kernel_launch(void* const* d_in, const int* in_sizes, int n_in,
                              void* d_out, int out_size, void* d_ws, size_t ws_size,
                              hipStream_t stream) {
    const int*   review_input  = (const int*)d_in[2];
    const int*   review_target = (const int*)d_in[3];
    const float* word_emb      = (const float*)d_in[4];
    const float* W_ih          = (const float*)d_in[5];
    const float* W_hh          = (const float*)d_in[6];
    const float* b_ih          = (const float*)d_in[7];
    const float* b_hh          = (const float*)d_in[8];
    const float* W_out         = (const float*)d_in[9];
    const float* b_out         = (const float*)d_in[10];
    float* out = (float*)d_out;

    char* ws = (char*)d_ws;
    size_t off = 0;
    auto alloc = [&](size_t n) { char* p = ws + off; off += (n + 255) & ~(size_t)255; return p; };
    unsigned short* Xb    = (unsigned short*)alloc((size_t)TOKENS * DIM * 2);
    unsigned short* Wihb  = (unsigned short*)alloc((size_t)G3 * DIM * 2);
    unsigned short* Whhb  = (unsigned short*)alloc((size_t)G3 * HID * 2);
    unsigned short* Woutb = (unsigned short*)alloc((size_t)VOCAB * DIM * 2);
    unsigned short* HS    = (unsigned short*)alloc((size_t)TOKENS * HID * 2);
    unsigned short* hzero = (unsigned short*)alloc((size_t)BATCH * HID * 2);
    float* hf      = (float*)alloc((size_t)BATCH * HID * 4);
    float* GI      = (float*)alloc((size_t)TOKENS * G3 * 4);
    float* partial = (float*)alloc((size_t)TOKENS * 512 * 4);
    float* lse     = (float*)alloc((size_t)TOKENS * 4);
    float* tlg     = (float*)alloc((size_t)TOKENS * 4);
    (void)ws_size; (void)in_sizes; (void)n_in; (void)out_size;

    // weight conversions + embedding gather
    k_cvt_bf16<<<dim3((G3 * DIM / 8 + 255) / 256), dim3(256), 0, stream>>>(W_ih, Wihb, G3 * DIM / 8);
    k_cvt_bf16<<<dim3((G3 * HID / 8 + 255) / 256), dim3(256), 0, stream>>>(W_hh, Whhb, G3 * HID / 8);
    k_cvt_bf16<<<dim3((VOCAB * DIM / 8 + 255) / 256), dim3(256), 0, stream>>>(W_out, Woutb, VOCAB * DIM / 8);
    k_gather_x<<<dim3(TOKENS * DIM / 8 / 256), dim3(256), 0, stream>>>(word_emb, review_input, Xb);

    // GI = X @ W_ih^T + b_ih
    k_gemm_gi<<<dim3(TOKENS / 64, G3 / 64), dim3(256), 0, stream>>>(Xb, Wihb, b_ih, GI);

    // GRU recurrence: 50 per-step kernels, 256 blocks x 64 thr (all CUs)
    hipMemsetAsync(hf, 0, (size_t)BATCH * HID * 4, stream);
    hipMemsetAsync(hzero, 0, (size_t)BATCH * HID * 2, stream);
    for (int s = 0; s < S_LEN; ++s) {
        const unsigned short* hin = s ? (HS + (size_t)(s - 1) * BATCH * HID) : hzero;
        unsigned short* hout = HS + (size_t)s * BATCH * HID;
        k_gru_step<<<dim3(256), dim3(64), 0, stream>>>(GI, Whhb, b_hh, hf, hin, hout, s);
    }

    // decode: partial exp-sums, reduce to lse, target logits, final loss
    k_decode<<<dim3(NWG), dim3(1024), 0, stream>>>(HS, Woutb, b_out, partial);
    k_reduce_lse<<<dim3(TOKENS / 4), dim3(256), 0, stream>>>(partial, lse);
    k_tlogit<<<dim3(TOKENS / 4), dim3(256), 0, stream>>>(HS, Woutb, b_out, review_target, tlg);
    k_finalize<<<dim3(1), dim3(256), 0, stream>>>(lse, tlg, review_target, out);
}